// Round 3
// baseline (1878.447 us; speedup 1.0000x reference)
//
#include <hip/hip_runtime.h>
#include <hip/hip_bf16.h>
#include <math.h>

#define L_TOK 138240
#define NW 960

typedef __attribute__((ext_vector_type(8))) short s16x8;
typedef __attribute__((ext_vector_type(8))) unsigned short u16x8;
typedef __attribute__((ext_vector_type(4))) float f32x4;

__device__ __forceinline__ float bf2f(unsigned short u){
  union{unsigned int u;float f;} v; v.u=((unsigned int)u)<<16; return v.f;
}
__device__ __forceinline__ unsigned short f2bf(float f){
  union{float f;unsigned int u;} v; v.f=f;
  unsigned int r = v.u + 0x7fffu + ((v.u>>16)&1u);
  return (unsigned short)(r>>16);
}

// ---------------- GEMM: out = op(A @ Bt^T + bias) ----------------
// A: M x K bf16 row-major; Bt: N x K bf16 row-major; bias: f32[N]
// MODE 0: bf16 out; MODE 1: gelu -> bf16 out; MODE 2: f32 out
template<int MODE>
__global__ __launch_bounds__(256) void gemm_bf16(
    const unsigned short* __restrict__ A,
    const unsigned short* __restrict__ Bt,
    const float* __restrict__ bias,
    void* __restrict__ out, int M, int N, int K)
{
  __shared__ unsigned short As[128][40];
  __shared__ unsigned short Bs[64][40];
  const int tid = threadIdx.x;
  const int wid = tid >> 6, lane = tid & 63;
  const int lr = lane & 15, kg = lane >> 4;
  const int bm = blockIdx.x, bn = blockIdx.y;
  const int wm = (wid >> 1) * 64, wn = (wid & 1) * 32;

  f32x4 acc[4][2] = {};

  for (int k0 = 0; k0 < K; k0 += 32) {
    __syncthreads();
    {
      int c = tid;
      int r = c >> 2, p = c & 3;
      *(u16x8*)&As[r][p*8] = *(const u16x8*)&A[(size_t)(bm*128+r)*K + k0 + p*8];
      c += 256; r = c >> 2; p = c & 3;
      *(u16x8*)&As[r][p*8] = *(const u16x8*)&A[(size_t)(bm*128+r)*K + k0 + p*8];
    }
    {
      int r = tid >> 2, p = tid & 3;
      *(u16x8*)&Bs[r][p*8] = *(const u16x8*)&Bt[(size_t)(bn*64+r)*K + k0 + p*8];
    }
    __syncthreads();

    s16x8 a[4], b[2];
    #pragma unroll
    for (int mi = 0; mi < 4; mi++) a[mi] = *(const s16x8*)&As[wm + mi*16 + lr][kg*8];
    #pragma unroll
    for (int ni = 0; ni < 2; ni++) b[ni] = *(const s16x8*)&Bs[wn + ni*16 + lr][kg*8];
    #pragma unroll
    for (int mi = 0; mi < 4; mi++)
      #pragma unroll
      for (int ni = 0; ni < 2; ni++)
        acc[mi][ni] = __builtin_amdgcn_mfma_f32_16x16x32_bf16(a[mi], b[ni], acc[mi][ni], 0, 0, 0);
  }

  #pragma unroll
  for (int mi = 0; mi < 4; mi++) {
    #pragma unroll
    for (int ni = 0; ni < 2; ni++) {
      const int col = bn*64 + wn + ni*16 + lr;
      const float bv = bias[col];
      #pragma unroll
      for (int q = 0; q < 4; q++) {
        const int row = bm*128 + wm + mi*16 + kg*4 + q;
        float v = acc[mi][ni][q] + bv;
        if (MODE == 1) v = 0.5f * v * (1.0f + erff(v * 0.70710678118654752f));
        if (MODE == 2) ((float*)out)[(size_t)row*N + col] = v;
        else           ((unsigned short*)out)[(size_t)row*N + col] = f2bf(v);
      }
    }
  }
}

// ---------------- Window attention, flash-strip (block = window x head) ----------------
__global__ __launch_bounds__(256) void attn_win(
    const unsigned short* __restrict__ qkv,   // L x 576 bf16 (3,heads,hd)
    const float* __restrict__ bias_mat,       // [6][144][144] f32 (this layer)
    unsigned short* __restrict__ attn_out,    // L x 192 bf16, natural row order
    int roll)
{
  __shared__ unsigned short Qs[144][40];
  __shared__ unsigned short Ks[144][40];
  __shared__ unsigned short Vs[32][160];      // V^T [hd][tok], tok padded to 160
  __shared__ unsigned short Pw[4][16][160];   // per-wave P strip
  __shared__ int lmap[144];
  __shared__ int regv[144];

  const int w = blockIdx.x, head = blockIdx.y;
  const int tid = threadIdx.x, wid = tid >> 6, lane = tid & 63;
  const int lr = lane & 15, kg = lane >> 4;
  const int ww = w % 15, hw = (w / 15) % 16, zw = w / 240;

  if (tid < 144) {
    const int z1 = tid / 72, h1 = (tid % 72) / 12, w1 = tid % 12;
    int z = zw*2 + z1, h = hw*6 + h1, x = ww*12 + w1;
    const int rz = (z < 6) ? 0 : ((z < 7) ? 1 : 2);
    const int rh = (h < 90) ? 0 : ((h < 93) ? 1 : 2);
    regv[tid] = rz*3 + rh;
    if (roll) { z = (z + 1) & 7; h = (h + 3) % 96; x = (x + 6) % 180; }
    lmap[tid] = (z*96 + h)*180 + x;
  }
  __syncthreads();

  for (int c = tid; c < 576; c += 256) {
    const int r = c >> 2, p = c & 3;
    const size_t base = (size_t)lmap[r]*576 + head*32 + p*8;
    *(u16x8*)&Qs[r][p*8] = *(const u16x8*)&qkv[base];
    *(u16x8*)&Ks[r][p*8] = *(const u16x8*)&qkv[base + 192];
  }
  for (int e = tid; e < 144*32; e += 256) {
    const int r = e >> 5, c = e & 31;
    Vs[c][r] = qkv[(size_t)lmap[r]*576 + 384 + head*32 + c];
  }
  for (int e = tid; e < 32*16; e += 256) Vs[e >> 4][144 + (e & 15)] = 0;
  __syncthreads();

  const float* bm_h = bias_mat + head*144*144;
  for (int s = wid; s < 9; s += 4) {
    const s16x8 a = *(const s16x8*)&Qs[s*16 + lr][kg*8];
    float pbuf[9][4];
    float mx[4] = {-3.0e38f, -3.0e38f, -3.0e38f, -3.0e38f};
    float sum[4] = {0.f, 0.f, 0.f, 0.f};

    #pragma unroll
    for (int ni = 0; ni < 9; ni++) {
      const s16x8 b = *(const s16x8*)&Ks[ni*16 + lr][kg*8];
      f32x4 acc = {0.f, 0.f, 0.f, 0.f};
      acc = __builtin_amdgcn_mfma_f32_16x16x32_bf16(a, b, acc, 0, 0, 0);
      #pragma unroll
      for (int q = 0; q < 4; q++) {
        const int row = s*16 + kg*4 + q, col = ni*16 + lr;
        float sv = acc[q] * 0.17677669529663687f + bm_h[row*144 + col];
        if (roll && (regv[row] != regv[col])) sv -= 1.0e9f;
        pbuf[ni][q] = sv;
        mx[q] = fmaxf(mx[q], sv);
      }
    }
    #pragma unroll
    for (int q = 0; q < 4; q++) {
      #pragma unroll
      for (int m = 1; m < 16; m <<= 1) mx[q] = fmaxf(mx[q], __shfl_xor(mx[q], m, 64));
    }
    #pragma unroll
    for (int ni = 0; ni < 9; ni++)
      #pragma unroll
      for (int q = 0; q < 4; q++) {
        const float p = __expf(pbuf[ni][q] - mx[q]);
        pbuf[ni][q] = p;
        sum[q] += p;
      }
    #pragma unroll
    for (int q = 0; q < 4; q++) {
      #pragma unroll
      for (int m = 1; m < 16; m <<= 1) sum[q] += __shfl_xor(sum[q], m, 64);
    }
    float inv[4];
    #pragma unroll
    for (int q = 0; q < 4; q++) inv[q] = 1.0f / sum[q];

    #pragma unroll
    for (int ni = 0; ni < 9; ni++)
      #pragma unroll
      for (int q = 0; q < 4; q++)
        Pw[wid][kg*4 + q][ni*16 + lr] = f2bf(pbuf[ni][q] * inv[q]);
    #pragma unroll
    for (int q = 0; q < 4; q++) Pw[wid][kg*4 + q][144 + lr] = 0;

    #pragma unroll
    for (int ci = 0; ci < 2; ci++) {
      f32x4 accO = {0.f, 0.f, 0.f, 0.f};
      #pragma unroll
      for (int ks = 0; ks < 5; ks++) {
        const s16x8 pa = *(const s16x8*)&Pw[wid][lr][ks*32 + kg*8];
        const s16x8 vb = *(const s16x8*)&Vs[ci*16 + lr][ks*32 + kg*8];
        accO = __builtin_amdgcn_mfma_f32_16x16x32_bf16(pa, vb, accO, 0, 0, 0);
      }
      #pragma unroll
      for (int q = 0; q < 4; q++) {
        const int row = s*16 + kg*4 + q;
        attn_out[(size_t)lmap[row]*192 + head*32 + ci*16 + lr] = f2bf(accO[q]);
      }
    }
  }
}

// ---------------- residual + LN: x += LN(y), f32 residual in d_out ----------------
__global__ __launch_bounds__(256) void ln_residual(
    const float* __restrict__ y, const float* __restrict__ g,
    const float* __restrict__ b, float* __restrict__ x,
    unsigned short* __restrict__ xb, int row0)
{
  const int row = row0 + blockIdx.x*4 + (threadIdx.x >> 6);
  const int lane = threadIdx.x & 63;
  const float* yr = y + (size_t)(row - row0)*192;
  const float v0 = yr[lane], v1 = yr[lane+64], v2 = yr[lane+128];
  float s = v0+v1+v2, ss = v0*v0+v1*v1+v2*v2;
  #pragma unroll
  for (int off = 32; off; off >>= 1) { s += __shfl_xor(s, off, 64); ss += __shfl_xor(ss, off, 64); }
  const float mu = s * (1.0f/192.0f);
  const float var = ss * (1.0f/192.0f) - mu*mu;
  const float rs = rsqrtf(var + 1e-5f);
  float* xr = x + (size_t)row*192;
  unsigned short* xbr = xb + (size_t)row*192;
  const float vv[3] = {v0, v1, v2};
  #pragma unroll
  for (int j = 0; j < 3; j++) {
    const int c = lane + j*64;
    const float o = (vv[j] - mu) * rs * g[c] + b[c];
    const float xn = xr[c] + o;
    xr[c] = xn; xbr[c] = f2bf(xn);
  }
}

// ---------------- helpers ----------------
__global__ void init_x(const float* __restrict__ xin, float* __restrict__ x,
                       unsigned short* __restrict__ xb, int n) {
  const int i = blockIdx.x*256 + threadIdx.x;
  if (i < n) { const float f = xin[i]; x[i] = f; xb[i] = f2bf(f); }
}
__global__ void copy_diag(const float* __restrict__ a, float* __restrict__ o, int n) {
  const int i = blockIdx.x*256 + threadIdx.x;
  if (i < n) o[i] = a[i] + 50.0f;   // distinct signature: ws too small
}
__global__ void scrub(float* __restrict__ o, int n) {
  const int i = blockIdx.x*256 + threadIdx.x;
  if (i < n) { const float v = o[i]; if (!isfinite(v)) o[i] = 100.0f; }
}
__global__ void transpose_w(const float* __restrict__ src, unsigned short* __restrict__ dst,
                            int K, int N) {  // src f32 [2][K][N] -> dst bf16 [2][N][K]
  const int i = blockIdx.x*256 + threadIdx.x;
  const int tot = K*N;
  if (i >= 2*tot) return;
  const int l = i / tot, e = i % tot;
  const int k = e / N, n = e % N;
  dst[(size_t)l*tot + (size_t)n*K + k] = f2bf(src[i]);
}
__global__ void build_bias(const float* __restrict__ tab, float* __restrict__ bm) {
  const int i = blockIdx.x*256 + threadIdx.x;  // [2][6][144][144]
  if (i >= 2*6*144*144) return;
  const int m = i % 144, n = (i/144) % 144, hd = (i/(144*144)) % 6, l = i/(144*144*6);
  const int z1 = n/72, h1 = (n%72)/12, w1 = n%12;
  const int z2 = m/72, h2 = (m%72)/12, w2 = m%12;
  const int idx = (z1 + 2*z2)*828 + (h1 + 6*h2)*23 + (w1 - w2 + 11);
  bm[i] = tab[(size_t)l*3312*6 + (size_t)idx*6 + hd];
}

extern "C" void kernel_launch(void* const* d_in, const int* in_sizes, int n_in,
                              void* d_out, int out_size, void* d_ws, size_t ws_size,
                              hipStream_t stream) {
  const float* x_in    = (const float*)d_in[0];
  const float* qkv_w   = (const float*)d_in[1];
  const float* qkv_b   = (const float*)d_in[2];
  const float* proj_w  = (const float*)d_in[3];
  const float* proj_b  = (const float*)d_in[4];
  const float* bias_tab= (const float*)d_in[5];
  const float* ln1_g   = (const float*)d_in[6];
  const float* ln1_b   = (const float*)d_in[7];
  const float* ln2_g   = (const float*)d_in[8];
  const float* ln2_b   = (const float*)d_in[9];
  const float* mlp_w1  = (const float*)d_in[10];
  const float* mlp_b1  = (const float*)d_in[11];
  const float* mlp_w2  = (const float*)d_in[12];
  const float* mlp_b2  = (const float*)d_in[13];

  const int nElem = L_TOK * 192;
  float* xf = (float*)d_out;                 // f32 residual stream lives in d_out

  // workspace layout (bytes)
  const size_t sz_R0 = 159252480;  // bf16 qkv L*576 | f32 y L*192 | bf16 h (L/2)*768
  const size_t sz_R1 = 53084160;   // bf16 attn_o L*192 | f32 y2 (L/2)*192
  const size_t sz_xb = 53084160;   // bf16 mirror of residual
  const size_t sz_wT = 1769472;    // bf16 transposed weights
  const size_t sz_bm = 995328;     // f32 bias matrices
  const size_t need  = sz_R0 + sz_R1 + sz_xb + sz_wT + sz_bm;  // ~255.8 MiB

  if (ws_size < need) {
    copy_diag<<<dim3((nElem+255)/256), 256, 0, stream>>>(x_in, xf, nElem);
    return;
  }

  char* ws = (char*)d_ws;
  hipMemsetAsync(ws, 0, need, stream);       // insurance: no garbage reads

  unsigned short* R0    = (unsigned short*)(ws);
  unsigned short* R1    = (unsigned short*)(ws + sz_R0);
  unsigned short* xb    = (unsigned short*)(ws + sz_R0 + sz_R1);
  unsigned short* wT    = (unsigned short*)(ws + sz_R0 + sz_R1 + sz_xb);
  float*          biasm = (float*)(ws + sz_R0 + sz_R1 + sz_xb + sz_wT);

  unsigned short* wT_qkv  = wT;            // 2 x 576 x 192
  unsigned short* wT_proj = wT + 221184;   // 2 x 192 x 192
  unsigned short* wT_m1   = wT + 294912;   // 2 x 768 x 192
  unsigned short* wT_m2   = wT + 589824;   // 2 x 192 x 768

  transpose_w<<<dim3((2*192*576+255)/256), 256, 0, stream>>>(qkv_w,  wT_qkv, 192, 576);
  transpose_w<<<dim3((2*192*192+255)/256), 256, 0, stream>>>(proj_w, wT_proj,192, 192);
  transpose_w<<<dim3((2*192*768+255)/256), 256, 0, stream>>>(mlp_w1, wT_m1,  192, 768);
  transpose_w<<<dim3((2*768*192+255)/256), 256, 0, stream>>>(mlp_w2, wT_m2,  768, 192);
  build_bias<<<dim3((2*6*144*144+255)/256), 256, 0, stream>>>(bias_tab, biasm);

  init_x<<<dim3((nElem+255)/256), 256, 0, stream>>>(x_in, xf, xb, nElem);

  const int Mh = L_TOK / 2;  // 69120 = 128*540
  for (int i = 0; i < 2; i++) {
    // QKV: xb -> R0 bf16 (L x 576)
    gemm_bf16<0><<<dim3(1080, 9), 256, 0, stream>>>(
        xb, wT_qkv + (size_t)i*110592, qkv_b + i*576, R0, L_TOK, 576, 192);
    // window attention: R0 -> R1 bf16 (natural row order)
    attn_win<<<dim3(NW, 6), 256, 0, stream>>>(
        R0, biasm + (size_t)i*6*144*144, R1, i & 1);
    // proj: R1 -> y f32 in R0 (qkv dead)
    gemm_bf16<2><<<dim3(1080, 3), 256, 0, stream>>>(
        R1, wT_proj + (size_t)i*36864, proj_b + i*192, (float*)R0, L_TOK, 192, 192);
    // x += LN(y)
    ln_residual<<<dim3(L_TOK/4), 256, 0, stream>>>(
        (const float*)R0, ln1_g + i*192, ln1_b + i*192, xf, xb, 0);
    // MLP in two M-halves: h bf16 in R0, y2 f32 in R1
    for (int hhalf = 0; hhalf < 2; hhalf++) {
      const unsigned short* Ah = xb + (size_t)hhalf*Mh*192;
      gemm_bf16<1><<<dim3(540, 12), 256, 0, stream>>>(
          Ah, wT_m1 + (size_t)i*147456, mlp_b1 + i*768, R0, Mh, 768, 192);
      gemm_bf16<2><<<dim3(540, 3), 256, 0, stream>>>(
          R0, wT_m2 + (size_t)i*147456, mlp_b2 + i*192, (float*)R1, Mh, 192, 768);
      ln_residual<<<dim3(Mh/4), 256, 0, stream>>>(
          (const float*)R1, ln2_g + i*192, ln2_b + i*192, xf, xb, hhalf*Mh);
    }
  }

  scrub<<<dim3((nElem+255)/256), 256, 0, stream>>>(xf, nElem);
}

// Round 4
// 1574.220 us; speedup vs baseline: 1.1933x; 1.1933x over previous
//
#include <hip/hip_runtime.h>
#include <hip/hip_bf16.h>
#include <math.h>

#define L_TOK 138240
#define NW 960

typedef __attribute__((ext_vector_type(8))) short s16x8;
typedef __attribute__((ext_vector_type(8))) unsigned short u16x8;
typedef __attribute__((ext_vector_type(4))) unsigned short u16x4;
typedef __attribute__((ext_vector_type(4))) float f32x4;

__device__ __forceinline__ float bf2f(unsigned short u){
  union{unsigned int u;float f;} v; v.u=((unsigned int)u)<<16; return v.f;
}
__device__ __forceinline__ unsigned short f2bf(float f){
  union{float f;unsigned int u;} v; v.f=f;
  unsigned int r = v.u + 0x7fffu + ((v.u>>16)&1u);
  return (unsigned short)(r>>16);
}
__device__ __forceinline__ void gll16(const void* g, void* l) {
  __builtin_amdgcn_global_load_lds((const __attribute__((address_space(1))) void*)g,
                                   (__attribute__((address_space(3))) void*)l, 16, 0, 0);
}

// ============ GEMM, A = f32 residual (reg-staged), B = bf16 wT (gload_lds) ============
// out bf16 = op(A @ Bt^T + bias); MODE 0 plain, 1 gelu
template<int MODE>
__global__ __launch_bounds__(256) void gemm_f32a(
    const float* __restrict__ A,            // M x K f32
    const unsigned short* __restrict__ Bt,  // N x K bf16
    const float* __restrict__ bias,         // f32[N]
    unsigned short* __restrict__ out, int M, int N, int K)
{
  __shared__ unsigned short As[2][128][40];   // padded, reg-staged
  __shared__ unsigned short Bs[2][64*32];     // linear, gload_lds
  const int tid = threadIdx.x;
  const int wid = tid >> 6, lane = tid & 63;
  const int lr = lane & 15, kg = lane >> 4;
  const int bm = blockIdx.x, bn = blockIdx.y;
  const int wm = (wid >> 1) * 64, wn = (wid & 1) * 32;
  const int rsub = lane >> 2, kc = lane & 3;

  f32x4 acc[4][2] = {};
  const int nst = K / 32;

  float4 av[4];
  // prologue: stage k0=0
  #pragma unroll
  for (int i = 0; i < 4; i++) {
    const int c = tid + i*256, r = c >> 3, c4 = c & 7;
    av[i] = *(const float4*)&A[(size_t)(bm*128 + r)*K + c4*4];
  }
  gll16(&Bt[(size_t)(bn*64 + wid*16 + rsub)*K + kc*8], &Bs[0][(wid*16)*32]);
  #pragma unroll
  for (int i = 0; i < 4; i++) {
    const int c = tid + i*256, r = c >> 3, c4 = c & 7;
    u16x4 t; t[0]=f2bf(av[i].x); t[1]=f2bf(av[i].y); t[2]=f2bf(av[i].z); t[3]=f2bf(av[i].w);
    *(u16x4*)&As[0][r][c4*4] = t;
  }
  __syncthreads();

  for (int t = 0; t < nst; t++) {
    const int cur = t & 1, nxt = cur ^ 1;
    if (t + 1 < nst) {
      gll16(&Bt[(size_t)(bn*64 + wid*16 + rsub)*K + (t+1)*32 + kc*8], &Bs[nxt][(wid*16)*32]);
      #pragma unroll
      for (int i = 0; i < 4; i++) {
        const int c = tid + i*256, r = c >> 3, c4 = c & 7;
        av[i] = *(const float4*)&A[(size_t)(bm*128 + r)*K + (t+1)*32 + c4*4];
      }
    }
    s16x8 a[4], b[2];
    #pragma unroll
    for (int mi = 0; mi < 4; mi++) a[mi] = *(const s16x8*)&As[cur][wm + mi*16 + lr][kg*8];
    #pragma unroll
    for (int ni = 0; ni < 2; ni++) b[ni] = *(const s16x8*)&Bs[cur][(wn + ni*16 + lr)*32 + kg*8];
    #pragma unroll
    for (int mi = 0; mi < 4; mi++)
      #pragma unroll
      for (int ni = 0; ni < 2; ni++)
        acc[mi][ni] = __builtin_amdgcn_mfma_f32_16x16x32_bf16(a[mi], b[ni], acc[mi][ni], 0, 0, 0);
    if (t + 1 < nst) {
      #pragma unroll
      for (int i = 0; i < 4; i++) {
        const int c = tid + i*256, r = c >> 3, c4 = c & 7;
        u16x4 tv; tv[0]=f2bf(av[i].x); tv[1]=f2bf(av[i].y); tv[2]=f2bf(av[i].z); tv[3]=f2bf(av[i].w);
        *(u16x4*)&As[nxt][r][c4*4] = tv;
      }
    }
    __syncthreads();
  }

  #pragma unroll
  for (int mi = 0; mi < 4; mi++) {
    #pragma unroll
    for (int ni = 0; ni < 2; ni++) {
      const int col = bn*64 + wn + ni*16 + lr;
      const float bv = bias[col];
      #pragma unroll
      for (int q = 0; q < 4; q++) {
        const int row = bm*128 + wm + mi*16 + kg*4 + q;
        float v = acc[mi][ni][q] + bv;
        if (MODE == 1) v = 0.5f * v * (1.0f + erff(v * 0.70710678118654752f));
        out[(size_t)row*N + col] = f2bf(v);
      }
    }
  }
}

// ============ GEMM + fused LN residual: x += LN(A @ Bt^T + bias) ============
// BN = 192 (full row). A bf16 (gload_lds), Bt bf16 [192][K].
__global__ __launch_bounds__(256) void gemm_ln(
    const unsigned short* __restrict__ A,   // Mloc x K bf16
    const unsigned short* __restrict__ Bt,  // 192 x K bf16
    const float* __restrict__ bias, const float* __restrict__ g,
    const float* __restrict__ bta,
    float* __restrict__ x,                  // full residual (d_out)
    int row0, int K)
{
  __shared__ unsigned short As[2][128*32];
  __shared__ unsigned short Bs[2][192*32];
  __shared__ float rowstat[128][2][2];
  const int tid = threadIdx.x;
  const int wid = tid >> 6, lane = tid & 63;
  const int lr = lane & 15, kg = lane >> 4;
  const int bm = blockIdx.x;
  const int wm = (wid >> 1) * 64, wn = (wid & 1) * 96;
  const int rsub = lane >> 2, kc = lane & 3;

  f32x4 acc[4][6] = {};
  const int nst = K / 32;

  // prologue stage
  #pragma unroll
  for (int i = 0; i < 2; i++)
    gll16(&A[(size_t)(bm*128 + wid*32 + i*16 + rsub)*K + kc*8], &As[0][(wid*32 + i*16)*32]);
  #pragma unroll
  for (int j = 0; j < 3; j++)
    gll16(&Bt[(size_t)(wid*48 + j*16 + rsub)*K + kc*8], &Bs[0][(wid*48 + j*16)*32]);
  __syncthreads();

  for (int t = 0; t < nst; t++) {
    const int cur = t & 1, nxt = cur ^ 1;
    if (t + 1 < nst) {
      const int k1 = (t+1)*32;
      #pragma unroll
      for (int i = 0; i < 2; i++)
        gll16(&A[(size_t)(bm*128 + wid*32 + i*16 + rsub)*K + k1 + kc*8], &As[nxt][(wid*32 + i*16)*32]);
      #pragma unroll
      for (int j = 0; j < 3; j++)
        gll16(&Bt[(size_t)(wid*48 + j*16 + rsub)*K + k1 + kc*8], &Bs[nxt][(wid*48 + j*16)*32]);
    }
    s16x8 a[4], b[6];
    #pragma unroll
    for (int mi = 0; mi < 4; mi++) a[mi] = *(const s16x8*)&As[cur][(wm + mi*16 + lr)*32 + kg*8];
    #pragma unroll
    for (int ni = 0; ni < 6; ni++) b[ni] = *(const s16x8*)&Bs[cur][(wn + ni*16 + lr)*32 + kg*8];
    #pragma unroll
    for (int mi = 0; mi < 4; mi++)
      #pragma unroll
      for (int ni = 0; ni < 6; ni++)
        acc[mi][ni] = __builtin_amdgcn_mfma_f32_16x16x32_bf16(a[mi], b[ni], acc[mi][ni], 0, 0, 0);
    __syncthreads();
  }

  float bv[6], gv[6], btv[6];
  #pragma unroll
  for (int ni = 0; ni < 6; ni++) {
    const int col = wn + ni*16 + lr;
    bv[ni] = bias[col]; gv[ni] = g[col]; btv[ni] = bta[col];
  }
  // pass 1: per-row partial stats over this wave's 96 cols
  #pragma unroll
  for (int mi = 0; mi < 4; mi++) {
    float s[4] = {0,0,0,0}, ss[4] = {0,0,0,0};
    #pragma unroll
    for (int ni = 0; ni < 6; ni++)
      #pragma unroll
      for (int q = 0; q < 4; q++) {
        const float v = acc[mi][ni][q] + bv[ni];
        s[q] += v; ss[q] += v*v;
      }
    #pragma unroll
    for (int q = 0; q < 4; q++) {
      #pragma unroll
      for (int m = 1; m < 16; m <<= 1) {
        s[q]  += __shfl_xor(s[q],  m, 64);
        ss[q] += __shfl_xor(ss[q], m, 64);
      }
    }
    if (lr == 0) {
      #pragma unroll
      for (int q = 0; q < 4; q++) {
        const int r = wm + mi*16 + kg*4 + q;
        rowstat[r][wid & 1][0] = s[q];
        rowstat[r][wid & 1][1] = ss[q];
      }
    }
  }
  __syncthreads();
  // pass 2: finalize LN + residual RMW
  #pragma unroll
  for (int mi = 0; mi < 4; mi++) {
    #pragma unroll
    for (int q = 0; q < 4; q++) {
      const int rl = wm + mi*16 + kg*4 + q;
      const float s  = rowstat[rl][0][0] + rowstat[rl][1][0];
      const float ss = rowstat[rl][0][1] + rowstat[rl][1][1];
      const float mu = s * (1.0f/192.0f);
      const float rs = rsqrtf(ss * (1.0f/192.0f) - mu*mu + 1e-5f);
      const size_t grow = (size_t)(row0 + bm*128 + rl) * 192;
      #pragma unroll
      for (int ni = 0; ni < 6; ni++) {
        const float v = acc[mi][ni][q] + bv[ni];
        const float o = (v - mu) * rs * gv[ni] + btv[ni];
        x[grow + wn + ni*16 + lr] += o;
      }
    }
  }
}

// ============ Window attention v2 (block = window x head) ============
__global__ __launch_bounds__(256) void attn_win2(
    const unsigned short* __restrict__ qkv,   // L x 576 bf16, Q pre-scaled
    const unsigned short* __restrict__ biasb, // [6][144col][144row] bf16, this layer
    unsigned short* __restrict__ attn_out,    // L x 192 bf16
    int roll)
{
  __shared__ unsigned short Ks[144][40];      // 11520
  __shared__ unsigned short Vs[32][168];      // 10752, V^T
  __shared__ unsigned short Pw[4][16][168];   // 21504, per-wave P strips
  __shared__ int lmap[144];
  __shared__ int regv[144];

  const int w = blockIdx.x, head = blockIdx.y;
  const int tid = threadIdx.x, wid = tid >> 6, lane = tid & 63;
  const int lr = lane & 15, kg = lane >> 4;
  const int ww = w % 15, hw = (w / 15) % 16, zw = w / 240;

  if (tid < 144) {
    const int z1 = tid / 72, h1 = (tid % 72) / 12, w1 = tid % 12;
    int z = zw*2 + z1, h = hw*6 + h1, xx = ww*12 + w1;
    const int rz = (z < 6) ? 0 : ((z < 7) ? 1 : 2);
    const int rh = (h < 90) ? 0 : ((h < 93) ? 1 : 2);
    regv[tid] = rz*3 + rh;
    if (roll) { z = (z + 1) & 7; h = (h + 3) % 96; xx = (xx + 6) % 180; }
    lmap[tid] = (z*96 + h)*180 + xx;
  }
  __syncthreads();

  unsigned short* Vrow = &Pw[0][0][0];        // [144][40] alias (transient)
  for (int c = tid; c < 576; c += 256) {
    const int r = c >> 2, p = c & 3;
    const size_t base = (size_t)lmap[r]*576 + head*32 + p*8;
    *(u16x8*)&Ks[r][p*8]       = *(const u16x8*)&qkv[base + 192];
    *(u16x8*)&Vrow[r*40 + p*8] = *(const u16x8*)&qkv[base + 384];
  }
  for (int e = tid; e < 32*16; e += 256) Vs[e >> 4][144 + (e & 15)] = 0;
  __syncthreads();
  for (int e = tid; e < 4608; e += 256) {     // in-LDS transpose, conflict-free orientation
    const int c = e / 144, r = e - c*144;
    Vs[c][r] = Vrow[r*40 + c];
  }
  __syncthreads();

  // zero-pad P cols 144..159 (Vrow now dead)
  #pragma unroll
  for (int j = 0; j < 4; j++) Pw[wid][lr][144 + kg*4 + j] = 0;

  const unsigned short* bb = biasb + (size_t)head*144*144;
  s16x8 kb[9];
  #pragma unroll
  for (int ni = 0; ni < 9; ni++) kb[ni] = *(const s16x8*)&Ks[ni*16 + lr][kg*8];

  for (int s = wid; s < 9; s += 4) {
    const int qrow = s*16 + lr;
    const s16x8 a = *(const s16x8*)&qkv[(size_t)lmap[qrow]*576 + head*32 + kg*8];
    u16x4 bb4[9];
    #pragma unroll
    for (int ni = 0; ni < 9; ni++)
      bb4[ni] = *(const u16x4*)&bb[(size_t)(ni*16 + lr)*144 + s*16 + kg*4];

    float pbuf[9][4];
    float mx[4] = {-3.0e38f, -3.0e38f, -3.0e38f, -3.0e38f};
    float sum[4] = {0.f, 0.f, 0.f, 0.f};
    #pragma unroll
    for (int ni = 0; ni < 9; ni++) {
      f32x4 acc = {0.f, 0.f, 0.f, 0.f};
      acc = __builtin_amdgcn_mfma_f32_16x16x32_bf16(a, kb[ni], acc, 0, 0, 0);
      #pragma unroll
      for (int q = 0; q < 4; q++) {
        const int row = s*16 + kg*4 + q, col = ni*16 + lr;
        float sv = acc[q] + bf2f(bb4[ni][q]);
        if (roll && (regv[row] != regv[col])) sv -= 1.0e9f;
        pbuf[ni][q] = sv;
        mx[q] = fmaxf(mx[q], sv);
      }
    }
    #pragma unroll
    for (int q = 0; q < 4; q++) {
      #pragma unroll
      for (int m = 1; m < 16; m <<= 1) mx[q] = fmaxf(mx[q], __shfl_xor(mx[q], m, 64));
    }
    #pragma unroll
    for (int ni = 0; ni < 9; ni++)
      #pragma unroll
      for (int q = 0; q < 4; q++) {
        const float p = __expf(pbuf[ni][q] - mx[q]);
        pbuf[ni][q] = p;
        sum[q] += p;
      }
    #pragma unroll
    for (int q = 0; q < 4; q++) {
      #pragma unroll
      for (int m = 1; m < 16; m <<= 1) sum[q] += __shfl_xor(sum[q], m, 64);
    }
    float inv[4];
    #pragma unroll
    for (int q = 0; q < 4; q++) inv[q] = 1.0f / sum[q];

    #pragma unroll
    for (int ni = 0; ni < 9; ni++)
      #pragma unroll
      for (int q = 0; q < 4; q++)
        Pw[wid][kg*4 + q][ni*16 + lr] = f2bf(pbuf[ni][q] * inv[q]);

    #pragma unroll
    for (int ci = 0; ci < 2; ci++) {
      f32x4 accO = {0.f, 0.f, 0.f, 0.f};
      #pragma unroll
      for (int ks = 0; ks < 5; ks++) {
        const s16x8 pa = *(const s16x8*)&Pw[wid][lr][ks*32 + kg*8];
        const s16x8 vb = *(const s16x8*)&Vs[ci*16 + lr][ks*32 + kg*8];
        accO = __builtin_amdgcn_mfma_f32_16x16x32_bf16(pa, vb, accO, 0, 0, 0);
      }
      #pragma unroll
      for (int q = 0; q < 4; q++) {
        const int row = s*16 + kg*4 + q;
        attn_out[(size_t)lmap[row]*192 + head*32 + ci*16 + lr] = f2bf(accO[q]);
      }
    }
  }
}

// ============ helpers ============
__global__ void init_x(const float* __restrict__ xin, float* __restrict__ x, int n) {
  const int i = blockIdx.x*256 + threadIdx.x;
  if (i < n) x[i] = xin[i];
}
__global__ void copy_diag(const float* __restrict__ a, float* __restrict__ o, int n) {
  const int i = blockIdx.x*256 + threadIdx.x;
  if (i < n) o[i] = a[i] + 50.0f;   // signature: ws too small
}
__global__ void transpose_w(const float* __restrict__ src, unsigned short* __restrict__ dst,
                            int K, int N, int nscale, float factor) {
  const int i = blockIdx.x*256 + threadIdx.x;
  const int tot = K*N;
  if (i >= 2*tot) return;
  const int l = i / tot, e = i % tot;
  const int k = e / N, n = e % N;
  float v = src[i];
  if (n < nscale) v *= factor;
  dst[(size_t)l*tot + (size_t)n*K + k] = f2bf(v);
}
__global__ void scale_qb(const float* __restrict__ src, float* __restrict__ dst) {
  const int i = blockIdx.x*256 + threadIdx.x;
  if (i >= 2*576) return;
  const float f = (i % 576) < 192 ? 0.17677669529663687f : 1.0f;
  dst[i] = src[i] * f;
}
__global__ void build_biasb(const float* __restrict__ tab, unsigned short* __restrict__ bm) {
  const int i = blockIdx.x*256 + threadIdx.x;  // [2][6][144col][144row]
  if (i >= 2*6*144*144) return;
  const int row = i % 144, col = (i/144) % 144, hd = (i/20736) % 6, l = i/124416;
  const int z1 = row/72, h1 = (row%72)/12, w1 = row%12;
  const int z2 = col/72, h2 = (col%72)/12, w2 = col%12;
  const int idx = (z1 + 2*z2)*828 + (h1 + 6*h2)*23 + (w1 - w2 + 11);
  bm[i] = f2bf(tab[(size_t)l*3312*6 + (size_t)idx*6 + hd]);
}

extern "C" void kernel_launch(void* const* d_in, const int* in_sizes, int n_in,
                              void* d_out, int out_size, void* d_ws, size_t ws_size,
                              hipStream_t stream) {
  const float* x_in    = (const float*)d_in[0];
  const float* qkv_w   = (const float*)d_in[1];
  const float* qkv_b   = (const float*)d_in[2];
  const float* proj_w  = (const float*)d_in[3];
  const float* proj_b  = (const float*)d_in[4];
  const float* bias_tab= (const float*)d_in[5];
  const float* ln1_g   = (const float*)d_in[6];
  const float* ln1_b   = (const float*)d_in[7];
  const float* ln2_g   = (const float*)d_in[8];
  const float* ln2_b   = (const float*)d_in[9];
  const float* mlp_w1  = (const float*)d_in[10];
  const float* mlp_b1  = (const float*)d_in[11];
  const float* mlp_w2  = (const float*)d_in[12];
  const float* mlp_b2  = (const float*)d_in[13];

  const int nElem = L_TOK * 192;
  float* xf = (float*)d_out;                 // f32 residual stream lives in d_out

  // workspace layout (bytes)
  const size_t sz_R0 = 159252480;  // bf16 qkv L*576 | bf16 h (L/2)*768
  const size_t sz_R1 = 53084160;   // bf16 attn_o L*192
  const size_t sz_wT = 1769472;    // bf16 transposed weights
  const size_t sz_bb = 497664;     // bf16 bias matrices [2][6][144][144]
  const size_t sz_qb = 4608;       // f32 scaled qkv bias
  const size_t need  = sz_R0 + sz_R1 + sz_wT + sz_bb + sz_qb;  // ~205 MiB

  if (ws_size < need) {
    copy_diag<<<dim3((nElem+255)/256), 256, 0, stream>>>(x_in, xf, nElem);
    return;
  }

  char* ws = (char*)d_ws;
  unsigned short* R0    = (unsigned short*)(ws);
  unsigned short* R1    = (unsigned short*)(ws + sz_R0);
  unsigned short* wT    = (unsigned short*)(ws + sz_R0 + sz_R1);
  unsigned short* biasb = (unsigned short*)(ws + sz_R0 + sz_R1 + sz_wT);
  float*          qb2   = (float*)(ws + sz_R0 + sz_R1 + sz_wT + sz_bb);

  unsigned short* wT_qkv  = wT;            // 2 x 576 x 192
  unsigned short* wT_proj = wT + 221184;   // 2 x 192 x 192
  unsigned short* wT_m1   = wT + 294912;   // 2 x 768 x 192
  unsigned short* wT_m2   = wT + 589824;   // 2 x 192 x 768

  transpose_w<<<dim3((2*192*576+255)/256), 256, 0, stream>>>(qkv_w,  wT_qkv, 192, 576, 192, 0.17677669529663687f);
  transpose_w<<<dim3((2*192*192+255)/256), 256, 0, stream>>>(proj_w, wT_proj,192, 192, 0, 1.0f);
  transpose_w<<<dim3((2*192*768+255)/256), 256, 0, stream>>>(mlp_w1, wT_m1,  192, 768, 0, 1.0f);
  transpose_w<<<dim3((2*768*192+255)/256), 256, 0, stream>>>(mlp_w2, wT_m2,  768, 192, 0, 1.0f);
  build_biasb<<<dim3((2*6*144*144+255)/256), 256, 0, stream>>>(bias_tab, biasb);
  scale_qb<<<dim3(5), 256, 0, stream>>>(qkv_b, qb2);

  init_x<<<dim3((nElem+255)/256), 256, 0, stream>>>(x_in, xf, nElem);

  const int Mh = L_TOK / 2;  // 69120 = 128*540
  for (int i = 0; i < 2; i++) {
    // QKV: x(f32) -> R0 bf16 (L x 576), Q pre-scaled
    gemm_f32a<0><<<dim3(1080, 9), 256, 0, stream>>>(
        xf, wT_qkv + (size_t)i*110592, qb2 + i*576, R0, L_TOK, 576, 192);
    // window attention: R0 -> R1 bf16
    attn_win2<<<dim3(NW, 6), 256, 0, stream>>>(
        R0, biasb + (size_t)i*124416, R1, i & 1);
    // proj + LN1 fused: x += LN(attn_o @ Wp + b)
    gemm_ln<<<dim3(1080), 256, 0, stream>>>(
        R1, wT_proj + (size_t)i*36864, proj_b + i*192,
        ln1_g + i*192, ln1_b + i*192, xf, 0, 192);
    // MLP in two M-halves (h reuses R0)
    for (int hh = 0; hh < 2; hh++) {
      gemm_f32a<1><<<dim3(540, 12), 256, 0, stream>>>(
          xf + (size_t)hh*Mh*192, wT_m1 + (size_t)i*147456, mlp_b1 + i*768, R0, Mh, 768, 192);
      gemm_ln<<<dim3(540), 256, 0, stream>>>(
          R0, wT_m2 + (size_t)i*147456, mlp_b2 + i*192,
          ln2_g + i*192, ln2_b + i*192, xf, hh*Mh, 768);
    }
  }
}

// Round 5
// 1467.991 us; speedup vs baseline: 1.2796x; 1.0724x over previous
//
#include <hip/hip_runtime.h>
#include <hip/hip_bf16.h>
#include <math.h>

#define L_TOK 138240
#define NW 960

typedef __attribute__((ext_vector_type(8))) short s16x8;
typedef __attribute__((ext_vector_type(8))) unsigned short u16x8;
typedef __attribute__((ext_vector_type(4))) unsigned short u16x4;
typedef __attribute__((ext_vector_type(4))) float f32x4;

__device__ __forceinline__ float bf2f(unsigned short u){
  union{unsigned int u;float f;} v; v.u=((unsigned int)u)<<16; return v.f;
}
__device__ __forceinline__ unsigned short f2bf(float f){
  union{float f;unsigned int u;} v; v.f=f;
  unsigned int r = v.u + 0x7fffu + ((v.u>>16)&1u);
  return (unsigned short)(r>>16);
}
__device__ __forceinline__ void gll16(const void* g, void* l) {
  __builtin_amdgcn_global_load_lds((const __attribute__((address_space(1))) void*)g,
                                   (__attribute__((address_space(3))) void*)l, 16, 0, 0);
}

// ============ Row-block GEMM: K=192, A f32 read ONCE, loop over N tiles ============
// A: M x 192 f32; Bt: N x 192 bf16 (L2-resident, read per-lane); out bf16.
// MODE 0 plain, 1 gelu. NTILES = N/64.
template<int MODE, int NTILES>
__global__ __launch_bounds__(256) void gemm_rowblk(
    const float* __restrict__ A,
    const unsigned short* __restrict__ Bt,
    const float* __restrict__ bias,
    unsigned short* __restrict__ out)
{
  __shared__ unsigned short As[128][200];   // 51.2 KB, padded pitch
  const int tid = threadIdx.x;
  const int wid = tid >> 6, lane = tid & 63;
  const int lr = lane & 15, kg = lane >> 4;
  const int bm = blockIdx.x;
  const int wm = (wid >> 1) * 64, wnh = (wid & 1) * 32;
  const int N = NTILES * 64;

  // stage A once: 128 x 192 f32 -> bf16 (24 float4 per thread)
  #pragma unroll
  for (int i = 0; i < 24; i++) {
    const int c = tid + i*256;            // 6144 chunks = 128 rows * 48
    const int r = c / 48, p = c % 48;
    const float4 v = *(const float4*)&A[(size_t)(bm*128 + r)*192 + p*4];
    u16x4 t; t[0]=f2bf(v.x); t[1]=f2bf(v.y); t[2]=f2bf(v.z); t[3]=f2bf(v.w);
    *(u16x4*)&As[r][p*4] = t;
  }
  __syncthreads();

  // hoist this wave's A fragments (reused for every N tile)
  s16x8 a[4][6];
  #pragma unroll
  for (int mi = 0; mi < 4; mi++)
    #pragma unroll
    for (int ks = 0; ks < 6; ks++)
      a[mi][ks] = *(const s16x8*)&As[wm + mi*16 + lr][ks*32 + kg*8];

  for (int bn = 0; bn < NTILES; bn++) {
    s16x8 b[2][6];
    #pragma unroll
    for (int ni = 0; ni < 2; ni++)
      #pragma unroll
      for (int ks = 0; ks < 6; ks++)
        b[ni][ks] = *(const s16x8*)&Bt[(size_t)(bn*64 + wnh + ni*16 + lr)*192 + ks*32 + kg*8];

    f32x4 acc[4][2] = {};
    #pragma unroll
    for (int ks = 0; ks < 6; ks++)
      #pragma unroll
      for (int mi = 0; mi < 4; mi++)
        #pragma unroll
        for (int ni = 0; ni < 2; ni++)
          acc[mi][ni] = __builtin_amdgcn_mfma_f32_16x16x32_bf16(a[mi][ks], b[ni][ks], acc[mi][ni], 0, 0, 0);

    #pragma unroll
    for (int mi = 0; mi < 4; mi++) {
      #pragma unroll
      for (int ni = 0; ni < 2; ni++) {
        const int col = bn*64 + wnh + ni*16 + lr;
        const float bv = bias[col];
        #pragma unroll
        for (int q = 0; q < 4; q++) {
          const int row = bm*128 + wm + mi*16 + kg*4 + q;
          float v = acc[mi][ni][q] + bv;
          if (MODE == 1) v = 0.5f * v * (1.0f + erff(v * 0.70710678118654752f));
          out[(size_t)row*N + col] = f2bf(v);
        }
      }
    }
  }
}

// ============ GEMM + fused LN residual: x += LN(A @ Bt^T + bias) ============
__global__ __launch_bounds__(256) void gemm_ln(
    const unsigned short* __restrict__ A,   // Mloc x K bf16
    const unsigned short* __restrict__ Bt,  // 192 x K bf16
    const float* __restrict__ bias, const float* __restrict__ g,
    const float* __restrict__ bta,
    float* __restrict__ x,                  // full residual (d_out)
    int row0, int K)
{
  __shared__ unsigned short As[2][128*32];
  __shared__ unsigned short Bs[2][192*32];
  __shared__ float rowstat[128][2][2];
  const int tid = threadIdx.x;
  const int wid = tid >> 6, lane = tid & 63;
  const int lr = lane & 15, kg = lane >> 4;
  const int bm = blockIdx.x;
  const int wm = (wid >> 1) * 64, wn = (wid & 1) * 96;
  const int rsub = lane >> 2, kc = lane & 3;

  f32x4 acc[4][6] = {};
  const int nst = K / 32;

  #pragma unroll
  for (int i = 0; i < 2; i++)
    gll16(&A[(size_t)(bm*128 + wid*32 + i*16 + rsub)*K + kc*8], &As[0][(wid*32 + i*16)*32]);
  #pragma unroll
  for (int j = 0; j < 3; j++)
    gll16(&Bt[(size_t)(wid*48 + j*16 + rsub)*K + kc*8], &Bs[0][(wid*48 + j*16)*32]);
  __syncthreads();

  for (int t = 0; t < nst; t++) {
    const int cur = t & 1, nxt = cur ^ 1;
    if (t + 1 < nst) {
      const int k1 = (t+1)*32;
      #pragma unroll
      for (int i = 0; i < 2; i++)
        gll16(&A[(size_t)(bm*128 + wid*32 + i*16 + rsub)*K + k1 + kc*8], &As[nxt][(wid*32 + i*16)*32]);
      #pragma unroll
      for (int j = 0; j < 3; j++)
        gll16(&Bt[(size_t)(wid*48 + j*16 + rsub)*K + k1 + kc*8], &Bs[nxt][(wid*48 + j*16)*32]);
    }
    s16x8 a[4], b[6];
    #pragma unroll
    for (int mi = 0; mi < 4; mi++) a[mi] = *(const s16x8*)&As[cur][(wm + mi*16 + lr)*32 + kg*8];
    #pragma unroll
    for (int ni = 0; ni < 6; ni++) b[ni] = *(const s16x8*)&Bs[cur][(wn + ni*16 + lr)*32 + kg*8];
    #pragma unroll
    for (int mi = 0; mi < 4; mi++)
      #pragma unroll
      for (int ni = 0; ni < 6; ni++)
        acc[mi][ni] = __builtin_amdgcn_mfma_f32_16x16x32_bf16(a[mi], b[ni], acc[mi][ni], 0, 0, 0);
    __syncthreads();
  }

  float bv[6], gv[6], btv[6];
  #pragma unroll
  for (int ni = 0; ni < 6; ni++) {
    const int col = wn + ni*16 + lr;
    bv[ni] = bias[col]; gv[ni] = g[col]; btv[ni] = bta[col];
  }
  #pragma unroll
  for (int mi = 0; mi < 4; mi++) {
    float s[4] = {0,0,0,0}, ss[4] = {0,0,0,0};
    #pragma unroll
    for (int ni = 0; ni < 6; ni++)
      #pragma unroll
      for (int q = 0; q < 4; q++) {
        const float v = acc[mi][ni][q] + bv[ni];
        s[q] += v; ss[q] += v*v;
      }
    #pragma unroll
    for (int q = 0; q < 4; q++) {
      #pragma unroll
      for (int m = 1; m < 16; m <<= 1) {
        s[q]  += __shfl_xor(s[q],  m, 64);
        ss[q] += __shfl_xor(ss[q], m, 64);
      }
    }
    if (lr == 0) {
      #pragma unroll
      for (int q = 0; q < 4; q++) {
        const int r = wm + mi*16 + kg*4 + q;
        rowstat[r][wid & 1][0] = s[q];
        rowstat[r][wid & 1][1] = ss[q];
      }
    }
  }
  __syncthreads();
  #pragma unroll
  for (int mi = 0; mi < 4; mi++) {
    #pragma unroll
    for (int q = 0; q < 4; q++) {
      const int rl = wm + mi*16 + kg*4 + q;
      const float s  = rowstat[rl][0][0] + rowstat[rl][1][0];
      const float ss = rowstat[rl][0][1] + rowstat[rl][1][1];
      const float mu = s * (1.0f/192.0f);
      const float rs = rsqrtf(ss * (1.0f/192.0f) - mu*mu + 1e-5f);
      const size_t grow = (size_t)(row0 + bm*128 + rl) * 192;
      #pragma unroll
      for (int ni = 0; ni < 6; ni++) {
        const float v = acc[mi][ni][q] + bv[ni];
        const float o = (v - mu) * rs * gv[ni] + btv[ni];
        x[grow + wn + ni*16 + lr] += o;
      }
    }
  }
}

// ============ Window attention v2 (block = window x head) ============
__global__ __launch_bounds__(256) void attn_win2(
    const unsigned short* __restrict__ qkv,   // L x 576 bf16, Q pre-scaled
    const unsigned short* __restrict__ biasb, // [6][144col][144row] bf16
    unsigned short* __restrict__ attn_out,    // L x 192 bf16
    int roll)
{
  __shared__ unsigned short Ks[144][40];
  __shared__ unsigned short Vs[32][168];
  __shared__ unsigned short Pw[4][16][168];
  __shared__ int lmap[144];
  __shared__ int regv[144];

  const int w = blockIdx.x, head = blockIdx.y;
  const int tid = threadIdx.x, wid = tid >> 6, lane = tid & 63;
  const int lr = lane & 15, kg = lane >> 4;
  const int ww = w % 15, hw = (w / 15) % 16, zw = w / 240;

  if (tid < 144) {
    const int z1 = tid / 72, h1 = (tid % 72) / 12, w1 = tid % 12;
    int z = zw*2 + z1, h = hw*6 + h1, xx = ww*12 + w1;
    const int rz = (z < 6) ? 0 : ((z < 7) ? 1 : 2);
    const int rh = (h < 90) ? 0 : ((h < 93) ? 1 : 2);
    regv[tid] = rz*3 + rh;
    if (roll) { z = (z + 1) & 7; h = (h + 3) % 96; xx = (xx + 6) % 180; }
    lmap[tid] = (z*96 + h)*180 + xx;
  }
  __syncthreads();

  unsigned short* Vrow = &Pw[0][0][0];
  for (int c = tid; c < 576; c += 256) {
    const int r = c >> 2, p = c & 3;
    const size_t base = (size_t)lmap[r]*576 + head*32 + p*8;
    *(u16x8*)&Ks[r][p*8]       = *(const u16x8*)&qkv[base + 192];
    *(u16x8*)&Vrow[r*40 + p*8] = *(const u16x8*)&qkv[base + 384];
  }
  for (int e = tid; e < 32*16; e += 256) Vs[e >> 4][144 + (e & 15)] = 0;
  __syncthreads();
  for (int e = tid; e < 4608; e += 256) {
    const int c = e / 144, r = e - c*144;
    Vs[c][r] = Vrow[r*40 + c];
  }
  __syncthreads();

  #pragma unroll
  for (int j = 0; j < 4; j++) Pw[wid][lr][144 + kg*4 + j] = 0;

  const unsigned short* bb = biasb + (size_t)head*144*144;
  s16x8 kb[9];
  #pragma unroll
  for (int ni = 0; ni < 9; ni++) kb[ni] = *(const s16x8*)&Ks[ni*16 + lr][kg*8];

  for (int s = wid; s < 9; s += 4) {
    const int qrow = s*16 + lr;
    const s16x8 a = *(const s16x8*)&qkv[(size_t)lmap[qrow]*576 + head*32 + kg*8];
    u16x4 bb4[9];
    #pragma unroll
    for (int ni = 0; ni < 9; ni++)
      bb4[ni] = *(const u16x4*)&bb[(size_t)(ni*16 + lr)*144 + s*16 + kg*4];

    float pbuf[9][4];
    float mx[4] = {-3.0e38f, -3.0e38f, -3.0e38f, -3.0e38f};
    float sum[4] = {0.f, 0.f, 0.f, 0.f};
    #pragma unroll
    for (int ni = 0; ni < 9; ni++) {
      f32x4 acc = {0.f, 0.f, 0.f, 0.f};
      acc = __builtin_amdgcn_mfma_f32_16x16x32_bf16(a, kb[ni], acc, 0, 0, 0);
      #pragma unroll
      for (int q = 0; q < 4; q++) {
        const int row = s*16 + kg*4 + q, col = ni*16 + lr;
        float sv = acc[q] + bf2f(bb4[ni][q]);
        if (roll && (regv[row] != regv[col])) sv -= 1.0e9f;
        pbuf[ni][q] = sv;
        mx[q] = fmaxf(mx[q], sv);
      }
    }
    #pragma unroll
    for (int q = 0; q < 4; q++) {
      #pragma unroll
      for (int m = 1; m < 16; m <<= 1) mx[q] = fmaxf(mx[q], __shfl_xor(mx[q], m, 64));
    }
    #pragma unroll
    for (int ni = 0; ni < 9; ni++)
      #pragma unroll
      for (int q = 0; q < 4; q++) {
        const float p = __expf(pbuf[ni][q] - mx[q]);
        pbuf[ni][q] = p;
        sum[q] += p;
      }
    #pragma unroll
    for (int q = 0; q < 4; q++) {
      #pragma unroll
      for (int m = 1; m < 16; m <<= 1) sum[q] += __shfl_xor(sum[q], m, 64);
    }
    float inv[4];
    #pragma unroll
    for (int q = 0; q < 4; q++) inv[q] = 1.0f / sum[q];

    #pragma unroll
    for (int ni = 0; ni < 9; ni++)
      #pragma unroll
      for (int q = 0; q < 4; q++)
        Pw[wid][kg*4 + q][ni*16 + lr] = f2bf(pbuf[ni][q] * inv[q]);

    #pragma unroll
    for (int ci = 0; ci < 2; ci++) {
      f32x4 accO = {0.f, 0.f, 0.f, 0.f};
      #pragma unroll
      for (int ks = 0; ks < 5; ks++) {
        const s16x8 pa = *(const s16x8*)&Pw[wid][lr][ks*32 + kg*8];
        const s16x8 vb = *(const s16x8*)&Vs[ci*16 + lr][ks*32 + kg*8];
        accO = __builtin_amdgcn_mfma_f32_16x16x32_bf16(pa, vb, accO, 0, 0, 0);
      }
      #pragma unroll
      for (int q = 0; q < 4; q++) {
        const int row = s*16 + kg*4 + q;
        attn_out[(size_t)lmap[row]*192 + head*32 + ci*16 + lr] = f2bf(accO[q]);
      }
    }
  }
}

// ============ helpers ============
__global__ void init_x(const float* __restrict__ xin, float* __restrict__ x, int n) {
  const int i = blockIdx.x*256 + threadIdx.x;
  if (i < n) x[i] = xin[i];
}
__global__ void copy_diag(const float* __restrict__ a, float* __restrict__ o, int n) {
  const int i = blockIdx.x*256 + threadIdx.x;
  if (i < n) o[i] = a[i] + 50.0f;
}
__global__ void transpose_w(const float* __restrict__ src, unsigned short* __restrict__ dst,
                            int K, int N, int nscale, float factor) {
  const int i = blockIdx.x*256 + threadIdx.x;
  const int tot = K*N;
  if (i >= 2*tot) return;
  const int l = i / tot, e = i % tot;
  const int k = e / N, n = e % N;
  float v = src[i];
  if (n < nscale) v *= factor;
  dst[(size_t)l*tot + (size_t)n*K + k] = f2bf(v);
}
__global__ void scale_qb(const float* __restrict__ src, float* __restrict__ dst) {
  const int i = blockIdx.x*256 + threadIdx.x;
  if (i >= 2*576) return;
  const float f = (i % 576) < 192 ? 0.17677669529663687f : 1.0f;
  dst[i] = src[i] * f;
}
__global__ void build_biasb(const float* __restrict__ tab, unsigned short* __restrict__ bm) {
  const int i = blockIdx.x*256 + threadIdx.x;  // [2][6][144col][144row]
  if (i >= 2*6*144*144) return;
  const int row = i % 144, col = (i/144) % 144, hd = (i/20736) % 6, l = i/124416;
  const int z1 = row/72, h1 = (row%72)/12, w1 = row%12;
  const int z2 = col/72, h2 = (col%72)/12, w2 = col%12;
  const int idx = (z1 + 2*z2)*828 + (h1 + 6*h2)*23 + (w1 - w2 + 11);
  bm[i] = f2bf(tab[(size_t)l*3312*6 + (size_t)idx*6 + hd]);
}

extern "C" void kernel_launch(void* const* d_in, const int* in_sizes, int n_in,
                              void* d_out, int out_size, void* d_ws, size_t ws_size,
                              hipStream_t stream) {
  const float* x_in    = (const float*)d_in[0];
  const float* qkv_w   = (const float*)d_in[1];
  const float* qkv_b   = (const float*)d_in[2];
  const float* proj_w  = (const float*)d_in[3];
  const float* proj_b  = (const float*)d_in[4];
  const float* bias_tab= (const float*)d_in[5];
  const float* ln1_g   = (const float*)d_in[6];
  const float* ln1_b   = (const float*)d_in[7];
  const float* ln2_g   = (const float*)d_in[8];
  const float* ln2_b   = (const float*)d_in[9];
  const float* mlp_w1  = (const float*)d_in[10];
  const float* mlp_b1  = (const float*)d_in[11];
  const float* mlp_w2  = (const float*)d_in[12];
  const float* mlp_b2  = (const float*)d_in[13];

  const int nElem = L_TOK * 192;
  float* xf = (float*)d_out;                 // f32 residual stream lives in d_out

  const size_t sz_R0 = 159252480;  // bf16 qkv L*576 | bf16 h (L/2)*768
  const size_t sz_R1 = 53084160;   // bf16 attn_o L*192
  const size_t sz_wT = 1769472;
  const size_t sz_bb = 497664;
  const size_t sz_qb = 4608;
  const size_t need  = sz_R0 + sz_R1 + sz_wT + sz_bb + sz_qb;

  if (ws_size < need) {
    copy_diag<<<dim3((nElem+255)/256), 256, 0, stream>>>(x_in, xf, nElem);
    return;
  }

  char* ws = (char*)d_ws;
  unsigned short* R0    = (unsigned short*)(ws);
  unsigned short* R1    = (unsigned short*)(ws + sz_R0);
  unsigned short* wT    = (unsigned short*)(ws + sz_R0 + sz_R1);
  unsigned short* biasb = (unsigned short*)(ws + sz_R0 + sz_R1 + sz_wT);
  float*          qb2   = (float*)(ws + sz_R0 + sz_R1 + sz_wT + sz_bb);

  unsigned short* wT_qkv  = wT;            // 2 x 576 x 192
  unsigned short* wT_proj = wT + 221184;   // 2 x 192 x 192
  unsigned short* wT_m1   = wT + 294912;   // 2 x 768 x 192
  unsigned short* wT_m2   = wT + 589824;   // 2 x 192 x 768

  transpose_w<<<dim3((2*192*576+255)/256), 256, 0, stream>>>(qkv_w,  wT_qkv, 192, 576, 192, 0.17677669529663687f);
  transpose_w<<<dim3((2*192*192+255)/256), 256, 0, stream>>>(proj_w, wT_proj,192, 192, 0, 1.0f);
  transpose_w<<<dim3((2*192*768+255)/256), 256, 0, stream>>>(mlp_w1, wT_m1,  192, 768, 0, 1.0f);
  transpose_w<<<dim3((2*768*192+255)/256), 256, 0, stream>>>(mlp_w2, wT_m2,  768, 192, 0, 1.0f);
  build_biasb<<<dim3((2*6*144*144+255)/256), 256, 0, stream>>>(bias_tab, biasb);
  scale_qb<<<dim3(5), 256, 0, stream>>>(qkv_b, qb2);

  init_x<<<dim3((nElem+255)/256), 256, 0, stream>>>(x_in, xf, nElem);

  const int Mh = L_TOK / 2;  // 69120 = 128*540
  for (int i = 0; i < 2; i++) {
    // QKV: x(f32) -> R0 bf16 (L x 576), Q pre-scaled; A read once per stripe
    gemm_rowblk<0, 9><<<dim3(1080), 256, 0, stream>>>(
        xf, wT_qkv + (size_t)i*110592, qb2 + i*576, R0);
    // window attention: R0 -> R1 bf16
    attn_win2<<<dim3(NW, 6), 256, 0, stream>>>(
        R0, biasb + (size_t)i*124416, R1, i & 1);
    // proj + LN1 fused: x += LN(attn_o @ Wp + b)
    gemm_ln<<<dim3(1080), 256, 0, stream>>>(
        R1, wT_proj + (size_t)i*36864, proj_b + i*192,
        ln1_g + i*192, ln1_b + i*192, xf, 0, 192);
    // MLP in two M-halves (h reuses R0)
    for (int hh = 0; hh < 2; hh++) {
      gemm_rowblk<1, 12><<<dim3(540), 256, 0, stream>>>(
          xf + (size_t)hh*Mh*192, wT_m1 + (size_t)i*147456, mlp_b1 + i*768, R0);
      gemm_ln<<<dim3(540), 256, 0, stream>>>(
          R0, wT_m2 + (size_t)i*147456, mlp_b2 + i*192,
          ln2_g + i*192, ln2_b + i*192, xf, hh*Mh, 768);
    }
  }
}